// Round 1
// 523.011 us; speedup vs baseline: 1.0111x; 1.0111x over previous
//
#include <hip/hip_runtime.h>

// AttackLSTM R16 — 8-wave rebalanced pipeline (one recurrent stage per SIMD).
// R15 counters: VALUBusy 50%, per-iter ~2168cy. Theory: per-iter time = busiest
// SIMD; old 6-wave layout put BOTH a0-rec and a2-rec on SIMD0 (2x everyone
// else). R16: 8 waves (512 thr), waves map round-robin wave&3 -> SIMD:
//   S0: w0 a0-rec      + w4 a1-proj g01
//   S1: w1 a1-rec      + w5 a1-proj g23
//   S2: w2 a2-rec      + w6 a2-proj g01
//   S3: w3 b-chain     + w7 a2-proj g23
// Peak-SIMD issue 256->192 fdot2 (+1 act chain instead of 2). Also:
// even/odd split accumulators (halve fdot2 dep-chain depth), s_setprio(1)
// around the recurrent waves (critical self-loops win arbitration vs proj).
// Pipeline depths unchanged: a0@v, a1proj@v-1, a1rec@v-2, a2proj@v-3,
// a2rec@v-4, b@v-5. pj slot written as two disjoint float2 halves.

#define BB 256
#define TT 512

typedef _Float16 v2h __attribute__((ext_vector_type(2)));

__device__ __forceinline__ float sig_(float x) {
  return __builtin_amdgcn_rcpf(1.f + __builtin_amdgcn_exp2f(-1.44269504f * x));
}
__device__ __forceinline__ float tanh_(float x) {
  return __builtin_fmaf(2.f, __builtin_amdgcn_rcpf(1.f + __builtin_amdgcn_exp2f(-2.88539008f * x)), -1.f);
}

template <int K>
__device__ __forceinline__ float qb_(float v) {
  return __int_as_float(__builtin_amdgcn_update_dpp(
      0, __float_as_int(v), (K | (K << 2) | (K << 4) | (K << 6)), 0xF, 0xF, true));
}

__device__ __forceinline__ void ldsbar_() {
  asm volatile("s_waitcnt lgkmcnt(0)\n\ts_barrier" ::: "memory");
}

#if __has_builtin(__builtin_amdgcn_fdot2)
#define FDOT2(acc, a, b) (acc) = __builtin_amdgcn_fdot2((a), (b), (acc), false)
#else
#define FDOT2(acc, a, b) \
  (acc) = __builtin_fmaf((float)(a)[0], (float)(b)[0], \
          __builtin_fmaf((float)(a)[1], (float)(b)[1], (acc)))
#endif
#define KEEPP(a) asm volatile("" : "+v"(a))
#define PIN32(w)                                                            \
  do {                                                                      \
    _Pragma("unroll") for (int _i = 0; _i < 32; ++_i) KEEPP((w)[_i]);       \
  } while (0)

__device__ __forceinline__ v2h bc2h_(int v) { return __builtin_bit_cast(v2h, v); }

// 64 halfs from LDS as 32 v2h via int4 reads (8x ds_read_b128).
__device__ __forceinline__ void load_h64(const _Float16* p, v2h hv[32]) {
  const int4* hp = reinterpret_cast<const int4*>(p);
#pragma unroll
  for (int i = 0; i < 8; ++i) {
    int4 blk = hp[i];
    hv[4 * i + 0] = bc2h_(blk.x);
    hv[4 * i + 1] = bc2h_(blk.y);
    hv[4 * i + 2] = bc2h_(blk.z);
    hv[4 * i + 3] = bc2h_(blk.w);
  }
}

// fp32 row of 64 -> 32 v2h.
__device__ __forceinline__ void load_row16(const float* src, v2h dst[32]) {
  const float4* p = reinterpret_cast<const float4*>(src);
#pragma unroll
  for (int i = 0; i < 16; ++i) {
    float4 v = p[i];
    dst[2 * i]     = v2h{(_Float16)v.x, (_Float16)v.y};
    dst[2 * i + 1] = v2h{(_Float16)v.z, (_Float16)v.w};
  }
}

// 4-gate dot, even/odd split accumulators (dep depth 16 instead of 32).
__device__ __forceinline__ void dot4_(const v2h w[4][32], const v2h hv[32],
                                      float& p0, float& p1, float& p2, float& p3) {
  float a0 = p0, a1 = p1, a2 = p2, a3 = p3;
  float b0 = 0.f, b1 = 0.f, b2 = 0.f, b3 = 0.f;
#pragma unroll
  for (int j = 0; j < 32; j += 2) {
    FDOT2(a0, w[0][j], hv[j]);         FDOT2(a1, w[1][j], hv[j]);
    FDOT2(a2, w[2][j], hv[j]);         FDOT2(a3, w[3][j], hv[j]);
    FDOT2(b0, w[0][j + 1], hv[j + 1]); FDOT2(b1, w[1][j + 1], hv[j + 1]);
    FDOT2(b2, w[2][j + 1], hv[j + 1]); FDOT2(b3, w[3][j + 1], hv[j + 1]);
  }
  p0 = a0 + b0; p1 = a1 + b1; p2 = a2 + b2; p3 = a3 + b3;
}

// 2-gate dot (projection halves), even/odd split.
__device__ __forceinline__ void dot2g_(const v2h* w0, const v2h* w1,
                                       const v2h hv[32], float& p0, float& p1) {
  float a0 = 0.f, a1 = 0.f, b0 = 0.f, b1 = 0.f;
#pragma unroll
  for (int j = 0; j < 32; j += 2) {
    FDOT2(a0, w0[j], hv[j]);         FDOT2(a1, w1[j], hv[j]);
    FDOT2(b0, w0[j + 1], hv[j + 1]); FDOT2(b1, w1[j + 1], hv[j + 1]);
  }
  p0 = a0 + b0; p1 = a1 + b1;
}

__global__ __attribute__((amdgpu_flat_work_group_size(512, 512),
                          amdgpu_waves_per_eu(1, 2)))
void lstm_pipe_k(
    const float* __restrict__ x,
    const float* __restrict__ wih_a0, const float* __restrict__ whh_a0,
    const float* __restrict__ bih_a0, const float* __restrict__ bhh_a0,
    const float* __restrict__ wih_a1, const float* __restrict__ whh_a1,
    const float* __restrict__ bih_a1, const float* __restrict__ bhh_a1,
    const float* __restrict__ wih_a2, const float* __restrict__ whh_a2,
    const float* __restrict__ bih_a2, const float* __restrict__ bhh_a2,
    const float* __restrict__ wih_b0, const float* __restrict__ whh_b0,
    const float* __restrict__ bih_b0, const float* __restrict__ bhh_b0,
    const float* __restrict__ wih_b1, const float* __restrict__ whh_b1,
    const float* __restrict__ bih_b1, const float* __restrict__ bhh_b1,
    const float* __restrict__ wih_b2, const float* __restrict__ whh_b2,
    const float* __restrict__ bih_b2, const float* __restrict__ bhh_b2,
    float* __restrict__ out)  // [B,T]
{
  // Discourage a 128-VGPR squeeze (R13: that spills); rec waves need ~190.
  asm volatile("" ::: "v190", "v191");

  const int b = blockIdx.x;
  const int tid = threadIdx.x;
  const int wave = tid >> 6;
  const int lane = tid & 63;

  __shared__ __align__(16) _Float16 hh[3 * 2 * 64];   // [layer][slot][hid]
  __shared__ __align__(16) float pj[2 * 2 * 64 * 4];  // [proj][slot][hid][gate]
  __shared__ float xs[TT];

  for (int i = tid; i < TT; i += 512) xs[i] = x[(size_t)b * TT + i];
  if (tid < 192) reinterpret_cast<int*>(hh)[tid] = 0;

  v2h wt[4][32];
  float bias[4] = {0.f, 0.f, 0.f, 0.f};
  float wi0_[4] = {0.f, 0.f, 0.f, 0.f};
  float whb0[4] = {}, wi1b[4] = {}, wh1b[4] = {}, bb1[4] = {},
        wi2b[4] = {}, wh2b[4] = {}, bb2[4] = {};

  if (wave == 0) {  // a0 recurrence
#pragma unroll
    for (int q = 0; q < 4; ++q) {
      const int row = q * 64 + lane;
      load_row16(whh_a0 + row * 64, wt[q]);
      bias[q] = bih_a0[row] + bhh_a0[row];
      wi0_[q] = wih_a0[row];
    }
    PIN32(wt[0]); PIN32(wt[1]); PIN32(wt[2]); PIN32(wt[3]);
  } else if (wave == 1) {  // a1 recurrence
#pragma unroll
    for (int q = 0; q < 4; ++q) {
      const int row = q * 64 + lane;
      load_row16(whh_a1 + row * 64, wt[q]);
      bias[q] = bih_a1[row] + bhh_a1[row];
    }
    PIN32(wt[0]); PIN32(wt[1]); PIN32(wt[2]); PIN32(wt[3]);
  } else if (wave == 2) {  // a2 recurrence
#pragma unroll
    for (int q = 0; q < 4; ++q) {
      const int row = q * 64 + lane;
      load_row16(whh_a2 + row * 64, wt[q]);
      bias[q] = bih_a2[row] + bhh_a2[row];
    }
    PIN32(wt[0]); PIN32(wt[1]); PIN32(wt[2]); PIN32(wt[3]);
  } else if (wave == 3) {  // b-chain
    const int q = lane & 3;
    load_row16(wih_b0 + q * 64, wt[0]);
    bias[0] = bih_b0[q] + bhh_b0[q];
#pragma unroll
    for (int k = 0; k < 4; ++k) {
      whb0[k] = whh_b0[k];
      wi1b[k] = wih_b1[k]; wh1b[k] = whh_b1[k]; bb1[k] = bih_b1[k] + bhh_b1[k];
      wi2b[k] = wih_b2[k]; wh2b[k] = whh_b2[k]; bb2[k] = bih_b2[k] + bhh_b2[k];
    }
    PIN32(wt[0]);
  } else if (wave == 4) {  // a1 proj gates 0,1
#pragma unroll
    for (int q = 0; q < 2; ++q) load_row16(wih_a1 + (q * 64 + lane) * 64, wt[q]);
    PIN32(wt[0]); PIN32(wt[1]);
  } else if (wave == 5) {  // a1 proj gates 2,3
#pragma unroll
    for (int q = 0; q < 2; ++q) load_row16(wih_a1 + ((q + 2) * 64 + lane) * 64, wt[q]);
    PIN32(wt[0]); PIN32(wt[1]);
  } else if (wave == 6) {  // a2 proj gates 0,1
#pragma unroll
    for (int q = 0; q < 2; ++q) load_row16(wih_a2 + (q * 64 + lane) * 64, wt[q]);
    PIN32(wt[0]); PIN32(wt[1]);
  } else {                 // a2 proj gates 2,3
#pragma unroll
    for (int q = 0; q < 2; ++q) load_row16(wih_a2 + ((q + 2) * 64 + lane) * 64, wt[q]);
    PIN32(wt[0]); PIN32(wt[1]);
  }
  __syncthreads();

  float c = 0.f;
  float h0b = 0.f, c0b = 0.f, h1b = 0.f, c1b = 0.f, h2b = 0.f, c2b = 0.f;

  for (int v = 0; v < TT + 5; ++v) {
    if (wave == 0) {  // a0 rec, t = v
      const int t = v;
      if (t < TT) {
        __builtin_amdgcn_s_setprio(1);
        v2h hv[32];
        load_h64(hh + 0 * 128 + ((t + 1) & 1) * 64, hv);
        const float xv = xs[t];
        float p0 = __builtin_fmaf(wi0_[0], xv, bias[0]);
        float p1 = __builtin_fmaf(wi0_[1], xv, bias[1]);
        float p2 = __builtin_fmaf(wi0_[2], xv, bias[2]);
        float p3 = __builtin_fmaf(wi0_[3], xv, bias[3]);
        dot4_(wt, hv, p0, p1, p2, p3);
        float gi = sig_(p0), gf = sig_(p1), gg = tanh_(p2), go = sig_(p3);
        c = __builtin_fmaf(gf, c, gi * gg);
        hh[0 * 128 + (t & 1) * 64 + lane] = (_Float16)(go * tanh_(c));
        __builtin_amdgcn_s_setprio(0);
      }
    } else if (wave == 1) {  // a1 rec, t = v-2
      const int t = v - 2;
      if (t >= 0 && t < TT) {
        __builtin_amdgcn_s_setprio(1);
        v2h hv[32];
        load_h64(hh + 1 * 128 + ((t + 1) & 1) * 64, hv);
        float4 pr = *reinterpret_cast<const float4*>(
            &pj[(0 * 2 + (t & 1)) * 256 + lane * 4]);
        float p0 = bias[0] + pr.x, p1 = bias[1] + pr.y;
        float p2 = bias[2] + pr.z, p3 = bias[3] + pr.w;
        dot4_(wt, hv, p0, p1, p2, p3);
        float gi = sig_(p0), gf = sig_(p1), gg = tanh_(p2), go = sig_(p3);
        c = __builtin_fmaf(gf, c, gi * gg);
        hh[1 * 128 + (t & 1) * 64 + lane] = (_Float16)(go * tanh_(c));
        __builtin_amdgcn_s_setprio(0);
      }
    } else if (wave == 2) {  // a2 rec, t = v-4
      const int t = v - 4;
      if (t >= 0 && t < TT) {
        __builtin_amdgcn_s_setprio(1);
        v2h hv[32];
        load_h64(hh + 2 * 128 + ((t + 1) & 1) * 64, hv);
        float4 pr = *reinterpret_cast<const float4*>(
            &pj[(1 * 2 + (t & 1)) * 256 + lane * 4]);
        float p0 = bias[0] + pr.x, p1 = bias[1] + pr.y;
        float p2 = bias[2] + pr.z, p3 = bias[3] + pr.w;
        dot4_(wt, hv, p0, p1, p2, p3);
        float gi = sig_(p0), gf = sig_(p1), gg = tanh_(p2), go = sig_(p3);
        c = __builtin_fmaf(gf, c, gi * gg);
        hh[2 * 128 + (t & 1) * 64 + lane] = (_Float16)(go * tanh_(c));
        __builtin_amdgcn_s_setprio(0);
      }
    } else if (wave == 3) {  // b-chain, t = v-5
      const int t = v - 5;
      if (t >= 0 && t < TT) {
        v2h hv[32];
        load_h64(hh + 2 * 128 + (t & 1) * 64, hv);
        float pga = bias[0], pgb = 0.f;
#pragma unroll
        for (int j = 0; j < 32; j += 2) {
          FDOT2(pga, wt[0][j], hv[j]);
          FDOT2(pgb, wt[0][j + 1], hv[j + 1]);
        }
        float pg = pga + pgb;
        float p_i = qb_<0>(pg), p_f = qb_<1>(pg), p_g = qb_<2>(pg), p_o = qb_<3>(pg);
        float i0 = sig_(__builtin_fmaf(whb0[0], h0b, p_i));
        float f0 = sig_(__builtin_fmaf(whb0[1], h0b, p_f));
        float g0 = tanh_(__builtin_fmaf(whb0[2], h0b, p_g));
        float o0 = sig_(__builtin_fmaf(whb0[3], h0b, p_o));
        c0b = __builtin_fmaf(f0, c0b, i0 * g0);
        h0b = o0 * tanh_(c0b);
        float i1 = sig_(bb1[0] + __builtin_fmaf(wi1b[0], h0b, wh1b[0] * h1b));
        float f1 = sig_(bb1[1] + __builtin_fmaf(wi1b[1], h0b, wh1b[1] * h1b));
        float g1 = tanh_(bb1[2] + __builtin_fmaf(wi1b[2], h0b, wh1b[2] * h1b));
        float o1 = sig_(bb1[3] + __builtin_fmaf(wi1b[3], h0b, wh1b[3] * h1b));
        c1b = __builtin_fmaf(f1, c1b, i1 * g1);
        h1b = o1 * tanh_(c1b);
        float i2 = sig_(bb2[0] + __builtin_fmaf(wi2b[0], h1b, wh2b[0] * h2b));
        float f2 = sig_(bb2[1] + __builtin_fmaf(wi2b[1], h1b, wh2b[1] * h2b));
        float g2 = tanh_(bb2[2] + __builtin_fmaf(wi2b[2], h1b, wh2b[2] * h2b));
        float o2 = sig_(bb2[3] + __builtin_fmaf(wi2b[3], h1b, wh2b[3] * h2b));
        c2b = __builtin_fmaf(f2, c2b, i2 * g2);
        h2b = o2 * tanh_(c2b);
        if (lane == 0) out[(size_t)b * TT + t] = h2b;
      }
    } else if (wave == 4) {  // a1 proj g01, t = v-1
      const int t = v - 1;
      if (t >= 0 && t < TT) {
        v2h hv[32];
        load_h64(hh + 0 * 128 + (t & 1) * 64, hv);
        float p0, p1;
        dot2g_(wt[0], wt[1], hv, p0, p1);
        *reinterpret_cast<float2*>(&pj[(0 * 2 + (t & 1)) * 256 + lane * 4]) =
            float2{p0, p1};
      }
    } else if (wave == 5) {  // a1 proj g23, t = v-1
      const int t = v - 1;
      if (t >= 0 && t < TT) {
        v2h hv[32];
        load_h64(hh + 0 * 128 + (t & 1) * 64, hv);
        float p2, p3;
        dot2g_(wt[0], wt[1], hv, p2, p3);
        *reinterpret_cast<float2*>(&pj[(0 * 2 + (t & 1)) * 256 + lane * 4 + 2]) =
            float2{p2, p3};
      }
    } else if (wave == 6) {  // a2 proj g01, t = v-3
      const int t = v - 3;
      if (t >= 0 && t < TT) {
        v2h hv[32];
        load_h64(hh + 1 * 128 + (t & 1) * 64, hv);
        float p0, p1;
        dot2g_(wt[0], wt[1], hv, p0, p1);
        *reinterpret_cast<float2*>(&pj[(1 * 2 + (t & 1)) * 256 + lane * 4]) =
            float2{p0, p1};
      }
    } else {                 // a2 proj g23, t = v-3
      const int t = v - 3;
      if (t >= 0 && t < TT) {
        v2h hv[32];
        load_h64(hh + 1 * 128 + (t & 1) * 64, hv);
        float p2, p3;
        dot2g_(wt[0], wt[1], hv, p2, p3);
        *reinterpret_cast<float2*>(&pj[(1 * 2 + (t & 1)) * 256 + lane * 4 + 2]) =
            float2{p2, p3};
      }
    }
    ldsbar_();
  }
}

extern "C" void kernel_launch(void* const* d_in, const int* in_sizes, int n_in,
                              void* d_out, int out_size, void* d_ws, size_t ws_size,
                              hipStream_t stream) {
  const float* x      = (const float*)d_in[0];
  const float* wih_a0 = (const float*)d_in[1];
  const float* whh_a0 = (const float*)d_in[2];
  const float* bih_a0 = (const float*)d_in[3];
  const float* bhh_a0 = (const float*)d_in[4];
  const float* wih_a1 = (const float*)d_in[5];
  const float* whh_a1 = (const float*)d_in[6];
  const float* bih_a1 = (const float*)d_in[7];
  const float* bhh_a1 = (const float*)d_in[8];
  const float* wih_a2 = (const float*)d_in[9];
  const float* whh_a2 = (const float*)d_in[10];
  const float* bih_a2 = (const float*)d_in[11];
  const float* bhh_a2 = (const float*)d_in[12];
  const float* wih_b0 = (const float*)d_in[13];
  const float* whh_b0 = (const float*)d_in[14];
  const float* bih_b0 = (const float*)d_in[15];
  const float* bhh_b0 = (const float*)d_in[16];
  const float* wih_b1 = (const float*)d_in[17];
  const float* whh_b1 = (const float*)d_in[18];
  const float* bih_b1 = (const float*)d_in[19];
  const float* bhh_b1 = (const float*)d_in[20];
  const float* wih_b2 = (const float*)d_in[21];
  const float* whh_b2 = (const float*)d_in[22];
  const float* bih_b2 = (const float*)d_in[23];
  const float* bhh_b2 = (const float*)d_in[24];
  float* out = (float*)d_out;

  lstm_pipe_k<<<BB, 512, 0, stream>>>(
      x,
      wih_a0, whh_a0, bih_a0, bhh_a0,
      wih_a1, whh_a1, bih_a1, bhh_a1,
      wih_a2, whh_a2, bih_a2, bhh_a2,
      wih_b0, whh_b0, bih_b0, bhh_b0,
      wih_b1, whh_b1, bih_b1, bhh_b1,
      wih_b2, whh_b2, bih_b2, bhh_b2,
      out);
}

// Round 2
// 401.485 us; speedup vs baseline: 1.3171x; 1.3027x over previous
//
#include <hip/hip_runtime.h>

// AttackLSTM R17 — CH=4 timesteps per barrier epoch (amortized sync).
// R16 post-mortem: 1.8x peak-SIMD issue cut bought only 2% -> NOT issue-bound.
// Cadence ~880ns/step >> ~480cy issue/SIMD/step => ~half of each iteration is
// recurring latency+sync: post-barrier LDS read (~120cy), lgkmcnt(0) drain,
// 8-wave s_barrier, per step x517. R17: pipeline skew deepened to 4 steps per
// stage per epoch; 8-slot rings (2xCH); barriers 517 -> 133. Rec waves resolve
// their own h(t-1)->h(t) dependency through same-wave LDS roundtrip (in-order
// DS pipe, no barrier). Window parity keeps reader/writer ring halves disjoint
// every epoch. bias/pj/x folded at dot END so post-barrier read latency
// overlaps dot issue. Inner CH loop NOT unrolled (I-cache ~9KB).
// Stage schedule (epoch e): w0 a0rec@e | w4,5 a1proj@e-1 | w1 a1rec@e-2 |
// w6,7 a2proj@e-3 | w2 a2rec@e-4 | w3 b-chain@e-5.

#define BB 256
#define TT 512
#define CH 4
#define NS 8  // ring slots = 2*CH

typedef _Float16 v2h __attribute__((ext_vector_type(2)));

__device__ __forceinline__ float sig_(float x) {
  return __builtin_amdgcn_rcpf(1.f + __builtin_amdgcn_exp2f(-1.44269504f * x));
}
__device__ __forceinline__ float tanh_(float x) {
  return __builtin_fmaf(2.f, __builtin_amdgcn_rcpf(1.f + __builtin_amdgcn_exp2f(-2.88539008f * x)), -1.f);
}

template <int K>
__device__ __forceinline__ float qb_(float v) {
  return __int_as_float(__builtin_amdgcn_update_dpp(
      0, __float_as_int(v), (K | (K << 2) | (K << 4) | (K << 6)), 0xF, 0xF, true));
}

__device__ __forceinline__ void ldsbar_() {
  asm volatile("s_waitcnt lgkmcnt(0)\n\ts_barrier" ::: "memory");
}

#if __has_builtin(__builtin_amdgcn_fdot2)
#define FDOT2(acc, a, b) (acc) = __builtin_amdgcn_fdot2((a), (b), (acc), false)
#else
#define FDOT2(acc, a, b) \
  (acc) = __builtin_fmaf((float)(a)[0], (float)(b)[0], \
          __builtin_fmaf((float)(a)[1], (float)(b)[1], (acc)))
#endif
#define KEEPP(a) asm volatile("" : "+v"(a))
#define PIN32(w)                                                            \
  do {                                                                      \
    _Pragma("unroll") for (int _i = 0; _i < 32; ++_i) KEEPP((w)[_i]);       \
  } while (0)

__device__ __forceinline__ v2h bc2h_(int v) { return __builtin_bit_cast(v2h, v); }

// 64 halfs from LDS as 32 v2h via int4 reads (8x ds_read_b128).
__device__ __forceinline__ void load_h64(const _Float16* p, v2h hv[32]) {
  const int4* hp = reinterpret_cast<const int4*>(p);
#pragma unroll
  for (int i = 0; i < 8; ++i) {
    int4 blk = hp[i];
    hv[4 * i + 0] = bc2h_(blk.x);
    hv[4 * i + 1] = bc2h_(blk.y);
    hv[4 * i + 2] = bc2h_(blk.z);
    hv[4 * i + 3] = bc2h_(blk.w);
  }
}

// fp32 row of 64 -> 32 v2h.
__device__ __forceinline__ void load_row16(const float* src, v2h dst[32]) {
  const float4* p = reinterpret_cast<const float4*>(src);
#pragma unroll
  for (int i = 0; i < 16; ++i) {
    float4 v = p[i];
    dst[2 * i]     = v2h{(_Float16)v.x, (_Float16)v.y};
    dst[2 * i + 1] = v2h{(_Float16)v.z, (_Float16)v.w};
  }
}

// 4-gate dot, even/odd split accumulators (dep depth 16). p holds init value.
__device__ __forceinline__ void dot4_(const v2h w[4][32], const v2h hv[32],
                                      float& p0, float& p1, float& p2, float& p3) {
  float a0 = p0, a1 = p1, a2 = p2, a3 = p3;
  float b0 = 0.f, b1 = 0.f, b2 = 0.f, b3 = 0.f;
#pragma unroll
  for (int j = 0; j < 32; j += 2) {
    FDOT2(a0, w[0][j], hv[j]);         FDOT2(a1, w[1][j], hv[j]);
    FDOT2(a2, w[2][j], hv[j]);         FDOT2(a3, w[3][j], hv[j]);
    FDOT2(b0, w[0][j + 1], hv[j + 1]); FDOT2(b1, w[1][j + 1], hv[j + 1]);
    FDOT2(b2, w[2][j + 1], hv[j + 1]); FDOT2(b3, w[3][j + 1], hv[j + 1]);
  }
  p0 = a0 + b0; p1 = a1 + b1; p2 = a2 + b2; p3 = a3 + b3;
}

// 2-gate dot (projection halves), even/odd split.
__device__ __forceinline__ void dot2g_(const v2h* w0, const v2h* w1,
                                       const v2h hv[32], float& p0, float& p1) {
  float a0 = 0.f, a1 = 0.f, b0 = 0.f, b1 = 0.f;
#pragma unroll
  for (int j = 0; j < 32; j += 2) {
    FDOT2(a0, w0[j], hv[j]);         FDOT2(a1, w1[j], hv[j]);
    FDOT2(b0, w0[j + 1], hv[j + 1]); FDOT2(b1, w1[j + 1], hv[j + 1]);
  }
  p0 = a0 + b0; p1 = a1 + b1;
}

__global__ __attribute__((amdgpu_flat_work_group_size(512, 512),
                          amdgpu_waves_per_eu(1, 2)))
void lstm_pipe_k(
    const float* __restrict__ x,
    const float* __restrict__ wih_a0, const float* __restrict__ whh_a0,
    const float* __restrict__ bih_a0, const float* __restrict__ bhh_a0,
    const float* __restrict__ wih_a1, const float* __restrict__ whh_a1,
    const float* __restrict__ bih_a1, const float* __restrict__ bhh_a1,
    const float* __restrict__ wih_a2, const float* __restrict__ whh_a2,
    const float* __restrict__ bih_a2, const float* __restrict__ bhh_a2,
    const float* __restrict__ wih_b0, const float* __restrict__ whh_b0,
    const float* __restrict__ bih_b0, const float* __restrict__ bhh_b0,
    const float* __restrict__ wih_b1, const float* __restrict__ whh_b1,
    const float* __restrict__ bih_b1, const float* __restrict__ bhh_b1,
    const float* __restrict__ wih_b2, const float* __restrict__ whh_b2,
    const float* __restrict__ bih_b2, const float* __restrict__ bhh_b2,
    float* __restrict__ out)  // [B,T]
{
  asm volatile("" ::: "v190", "v191");

  const int b = blockIdx.x;
  const int tid = threadIdx.x;
  const int wave = tid >> 6;
  const int lane = tid & 63;

  __shared__ __align__(16) _Float16 hh[3][NS][64];  // h rings
  __shared__ __align__(16) float pj[2][NS][256];    // proj rings [hid][gate]
  __shared__ float xs[TT];

  for (int i = tid; i < TT; i += 512) xs[i] = x[(size_t)b * TT + i];
  for (int i = tid; i < 3 * NS * 64 / 2; i += 512) reinterpret_cast<int*>(hh)[i] = 0;

  v2h wt[4][32];
  float bias[4] = {0.f, 0.f, 0.f, 0.f};
  float wi0_[4] = {0.f, 0.f, 0.f, 0.f};
  float whb0[4] = {}, wi1b[4] = {}, wh1b[4] = {}, bb1[4] = {},
        wi2b[4] = {}, wh2b[4] = {}, bb2[4] = {};

  if (wave == 0) {  // a0 recurrence
#pragma unroll
    for (int q = 0; q < 4; ++q) {
      const int row = q * 64 + lane;
      load_row16(whh_a0 + row * 64, wt[q]);
      bias[q] = bih_a0[row] + bhh_a0[row];
      wi0_[q] = wih_a0[row];
    }
    PIN32(wt[0]); PIN32(wt[1]); PIN32(wt[2]); PIN32(wt[3]);
  } else if (wave == 1) {  // a1 recurrence
#pragma unroll
    for (int q = 0; q < 4; ++q) {
      const int row = q * 64 + lane;
      load_row16(whh_a1 + row * 64, wt[q]);
      bias[q] = bih_a1[row] + bhh_a1[row];
    }
    PIN32(wt[0]); PIN32(wt[1]); PIN32(wt[2]); PIN32(wt[3]);
  } else if (wave == 2) {  // a2 recurrence
#pragma unroll
    for (int q = 0; q < 4; ++q) {
      const int row = q * 64 + lane;
      load_row16(whh_a2 + row * 64, wt[q]);
      bias[q] = bih_a2[row] + bhh_a2[row];
    }
    PIN32(wt[0]); PIN32(wt[1]); PIN32(wt[2]); PIN32(wt[3]);
  } else if (wave == 3) {  // b-chain
    const int q = lane & 3;
    load_row16(wih_b0 + q * 64, wt[0]);
    bias[0] = bih_b0[q] + bhh_b0[q];
#pragma unroll
    for (int k = 0; k < 4; ++k) {
      whb0[k] = whh_b0[k];
      wi1b[k] = wih_b1[k]; wh1b[k] = whh_b1[k]; bb1[k] = bih_b1[k] + bhh_b1[k];
      wi2b[k] = wih_b2[k]; wh2b[k] = whh_b2[k]; bb2[k] = bih_b2[k] + bhh_b2[k];
    }
    PIN32(wt[0]);
  } else if (wave == 4) {  // a1 proj gates 0,1
#pragma unroll
    for (int q = 0; q < 2; ++q) load_row16(wih_a1 + (q * 64 + lane) * 64, wt[q]);
    PIN32(wt[0]); PIN32(wt[1]);
  } else if (wave == 5) {  // a1 proj gates 2,3
#pragma unroll
    for (int q = 0; q < 2; ++q) load_row16(wih_a1 + ((q + 2) * 64 + lane) * 64, wt[q]);
    PIN32(wt[0]); PIN32(wt[1]);
  } else if (wave == 6) {  // a2 proj gates 0,1
#pragma unroll
    for (int q = 0; q < 2; ++q) load_row16(wih_a2 + (q * 64 + lane) * 64, wt[q]);
    PIN32(wt[0]); PIN32(wt[1]);
  } else {                 // a2 proj gates 2,3
#pragma unroll
    for (int q = 0; q < 2; ++q) load_row16(wih_a2 + ((q + 2) * 64 + lane) * 64, wt[q]);
    PIN32(wt[0]); PIN32(wt[1]);
  }
  __syncthreads();

  float c = 0.f;
  float h0b = 0.f, c0b = 0.f, h1b = 0.f, c1b = 0.f, h2b = 0.f, c2b = 0.f;

  const int NE = TT / CH + 5;
  for (int e = 0; e < NE; ++e) {
    if (wave == 0) {  // a0 rec, window e
      const int t0 = e * CH;
      if (t0 < TT) {
        __builtin_amdgcn_s_setprio(1);
        for (int s = 0; s < CH; ++s) {
          const int t = t0 + s;
          v2h hv[32];
          load_h64(&hh[0][(t + NS - 1) & (NS - 1)][0], hv);
          const float xv = xs[t];
          float p0 = bias[0], p1 = bias[1], p2 = bias[2], p3 = bias[3];
          dot4_(wt, hv, p0, p1, p2, p3);
          p0 = __builtin_fmaf(wi0_[0], xv, p0);
          p1 = __builtin_fmaf(wi0_[1], xv, p1);
          p2 = __builtin_fmaf(wi0_[2], xv, p2);
          p3 = __builtin_fmaf(wi0_[3], xv, p3);
          float gi = sig_(p0), gf = sig_(p1), gg = tanh_(p2), go = sig_(p3);
          c = __builtin_fmaf(gf, c, gi * gg);
          hh[0][t & (NS - 1)][lane] = (_Float16)(go * tanh_(c));
          asm volatile("s_waitcnt lgkmcnt(0)" ::: "memory");
        }
        __builtin_amdgcn_s_setprio(0);
      }
    } else if (wave == 1) {  // a1 rec, window e-2
      const int t0 = (e - 2) * CH;
      if (t0 >= 0 && t0 < TT) {
        __builtin_amdgcn_s_setprio(1);
        for (int s = 0; s < CH; ++s) {
          const int t = t0 + s;
          v2h hv[32];
          load_h64(&hh[1][(t + NS - 1) & (NS - 1)][0], hv);
          float4 pr = *reinterpret_cast<const float4*>(&pj[0][t & (NS - 1)][lane * 4]);
          float p0 = bias[0], p1 = bias[1], p2 = bias[2], p3 = bias[3];
          dot4_(wt, hv, p0, p1, p2, p3);
          p0 += pr.x; p1 += pr.y; p2 += pr.z; p3 += pr.w;
          float gi = sig_(p0), gf = sig_(p1), gg = tanh_(p2), go = sig_(p3);
          c = __builtin_fmaf(gf, c, gi * gg);
          hh[1][t & (NS - 1)][lane] = (_Float16)(go * tanh_(c));
          asm volatile("s_waitcnt lgkmcnt(0)" ::: "memory");
        }
        __builtin_amdgcn_s_setprio(0);
      }
    } else if (wave == 2) {  // a2 rec, window e-4
      const int t0 = (e - 4) * CH;
      if (t0 >= 0 && t0 < TT) {
        __builtin_amdgcn_s_setprio(1);
        for (int s = 0; s < CH; ++s) {
          const int t = t0 + s;
          v2h hv[32];
          load_h64(&hh[2][(t + NS - 1) & (NS - 1)][0], hv);
          float4 pr = *reinterpret_cast<const float4*>(&pj[1][t & (NS - 1)][lane * 4]);
          float p0 = bias[0], p1 = bias[1], p2 = bias[2], p3 = bias[3];
          dot4_(wt, hv, p0, p1, p2, p3);
          p0 += pr.x; p1 += pr.y; p2 += pr.z; p3 += pr.w;
          float gi = sig_(p0), gf = sig_(p1), gg = tanh_(p2), go = sig_(p3);
          c = __builtin_fmaf(gf, c, gi * gg);
          hh[2][t & (NS - 1)][lane] = (_Float16)(go * tanh_(c));
          asm volatile("s_waitcnt lgkmcnt(0)" ::: "memory");
        }
        __builtin_amdgcn_s_setprio(0);
      }
    } else if (wave == 3) {  // b-chain, window e-5
      const int t0 = (e - 5) * CH;
      if (t0 >= 0 && t0 < TT) {
        for (int s = 0; s < CH; ++s) {
          const int t = t0 + s;
          v2h hv[32];
          load_h64(&hh[2][t & (NS - 1)][0], hv);
          float pga = bias[0], pgb = 0.f;
#pragma unroll
          for (int j = 0; j < 32; j += 2) {
            FDOT2(pga, wt[0][j], hv[j]);
            FDOT2(pgb, wt[0][j + 1], hv[j + 1]);
          }
          float pg = pga + pgb;
          float p_i = qb_<0>(pg), p_f = qb_<1>(pg), p_g = qb_<2>(pg), p_o = qb_<3>(pg);
          float i0 = sig_(__builtin_fmaf(whb0[0], h0b, p_i));
          float f0 = sig_(__builtin_fmaf(whb0[1], h0b, p_f));
          float g0 = tanh_(__builtin_fmaf(whb0[2], h0b, p_g));
          float o0 = sig_(__builtin_fmaf(whb0[3], h0b, p_o));
          c0b = __builtin_fmaf(f0, c0b, i0 * g0);
          h0b = o0 * tanh_(c0b);
          float i1 = sig_(bb1[0] + __builtin_fmaf(wi1b[0], h0b, wh1b[0] * h1b));
          float f1 = sig_(bb1[1] + __builtin_fmaf(wi1b[1], h0b, wh1b[1] * h1b));
          float g1 = tanh_(bb1[2] + __builtin_fmaf(wi1b[2], h0b, wh1b[2] * h1b));
          float o1 = sig_(bb1[3] + __builtin_fmaf(wi1b[3], h0b, wh1b[3] * h1b));
          c1b = __builtin_fmaf(f1, c1b, i1 * g1);
          h1b = o1 * tanh_(c1b);
          float i2 = sig_(bb2[0] + __builtin_fmaf(wi2b[0], h1b, wh2b[0] * h2b));
          float f2 = sig_(bb2[1] + __builtin_fmaf(wi2b[1], h1b, wh2b[1] * h2b));
          float g2 = tanh_(bb2[2] + __builtin_fmaf(wi2b[2], h1b, wh2b[2] * h2b));
          float o2 = sig_(bb2[3] + __builtin_fmaf(wi2b[3], h1b, wh2b[3] * h2b));
          c2b = __builtin_fmaf(f2, c2b, i2 * g2);
          h2b = o2 * tanh_(c2b);
          if (lane == 0) out[(size_t)b * TT + t] = h2b;
        }
      }
    } else if (wave == 4) {  // a1 proj g01, window e-1
      const int t0 = (e - 1) * CH;
      if (t0 >= 0 && t0 < TT) {
        for (int s = 0; s < CH; ++s) {
          const int t = t0 + s;
          v2h hv[32];
          load_h64(&hh[0][t & (NS - 1)][0], hv);
          float p0, p1;
          dot2g_(wt[0], wt[1], hv, p0, p1);
          *reinterpret_cast<float2*>(&pj[0][t & (NS - 1)][lane * 4]) = float2{p0, p1};
        }
      }
    } else if (wave == 5) {  // a1 proj g23, window e-1
      const int t0 = (e - 1) * CH;
      if (t0 >= 0 && t0 < TT) {
        for (int s = 0; s < CH; ++s) {
          const int t = t0 + s;
          v2h hv[32];
          load_h64(&hh[0][t & (NS - 1)][0], hv);
          float p2, p3;
          dot2g_(wt[0], wt[1], hv, p2, p3);
          *reinterpret_cast<float2*>(&pj[0][t & (NS - 1)][lane * 4 + 2]) = float2{p2, p3};
        }
      }
    } else if (wave == 6) {  // a2 proj g01, window e-3
      const int t0 = (e - 3) * CH;
      if (t0 >= 0 && t0 < TT) {
        for (int s = 0; s < CH; ++s) {
          const int t = t0 + s;
          v2h hv[32];
          load_h64(&hh[1][t & (NS - 1)][0], hv);
          float p0, p1;
          dot2g_(wt[0], wt[1], hv, p0, p1);
          *reinterpret_cast<float2*>(&pj[1][t & (NS - 1)][lane * 4]) = float2{p0, p1};
        }
      }
    } else {                 // a2 proj g23, window e-3
      const int t0 = (e - 3) * CH;
      if (t0 >= 0 && t0 < TT) {
        for (int s = 0; s < CH; ++s) {
          const int t = t0 + s;
          v2h hv[32];
          load_h64(&hh[1][t & (NS - 1)][0], hv);
          float p2, p3;
          dot2g_(wt[0], wt[1], hv, p2, p3);
          *reinterpret_cast<float2*>(&pj[1][t & (NS - 1)][lane * 4 + 2]) = float2{p2, p3};
        }
      }
    }
    ldsbar_();
  }
}

extern "C" void kernel_launch(void* const* d_in, const int* in_sizes, int n_in,
                              void* d_out, int out_size, void* d_ws, size_t ws_size,
                              hipStream_t stream) {
  const float* x      = (const float*)d_in[0];
  const float* wih_a0 = (const float*)d_in[1];
  const float* whh_a0 = (const float*)d_in[2];
  const float* bih_a0 = (const float*)d_in[3];
  const float* bhh_a0 = (const float*)d_in[4];
  const float* wih_a1 = (const float*)d_in[5];
  const float* whh_a1 = (const float*)d_in[6];
  const float* bih_a1 = (const float*)d_in[7];
  const float* bhh_a1 = (const float*)d_in[8];
  const float* wih_a2 = (const float*)d_in[9];
  const float* whh_a2 = (const float*)d_in[10];
  const float* bih_a2 = (const float*)d_in[11];
  const float* bhh_a2 = (const float*)d_in[12];
  const float* wih_b0 = (const float*)d_in[13];
  const float* whh_b0 = (const float*)d_in[14];
  const float* bih_b0 = (const float*)d_in[15];
  const float* bhh_b0 = (const float*)d_in[16];
  const float* wih_b1 = (const float*)d_in[17];
  const float* whh_b1 = (const float*)d_in[18];
  const float* bih_b1 = (const float*)d_in[19];
  const float* bhh_b1 = (const float*)d_in[20];
  const float* wih_b2 = (const float*)d_in[21];
  const float* whh_b2 = (const float*)d_in[22];
  const float* bih_b2 = (const float*)d_in[23];
  const float* bhh_b2 = (const float*)d_in[24];
  float* out = (float*)d_out;

  lstm_pipe_k<<<BB, 512, 0, stream>>>(
      x,
      wih_a0, whh_a0, bih_a0, bhh_a0,
      wih_a1, whh_a1, bih_a1, bhh_a1,
      wih_a2, whh_a2, bih_a2, bhh_a2,
      wih_b0, whh_b0, bih_b0, bhh_b0,
      wih_b1, whh_b1, bih_b1, bhh_b1,
      wih_b2, whh_b2, bih_b2, bhh_b2,
      out);
}

// Round 3
// 401.123 us; speedup vs baseline: 1.3183x; 1.0009x over previous
//
#include <hip/hip_runtime.h>

// AttackLSTM R18 — pk_fma_f16 dots + forced arch-VGPR=208 + CH=8 epochs.
// R17 post-mortem: VALUBusy 70% @ 1534cy/step but static count predicts ~540
// issue-cy/SIMD/step -> factor 2 unexplained. VGPR_Count=128 with ~175 live
// values in rec waves => weights parked in AGPRs; v_dot2/VOP3P can't source
// AGPRs (R14 lesson) -> v_accvgpr_read per weight use = the missing cycles.
// The R15 clobber hack (v190/191) silently failed at 512 threads.
// R18: (1) waves_per_eu(2,2) + clobber v204-v207 -> arch ~208, 2 waves/SIMD
// preserved (2x208+agpr <= 512/SIMD). (2) dots as v_pk_fma_f16 (2 v2h accs
// per gate, depth-16 f16 chains; combine via fdot2 with {1,1}) — full packed
// rate, VOP3P-addressable weights. (3) CH=8, NS=16 rings: barriers 133->69.
// (4) per-step lgkmcnt(0) dropped in rec loops (per-wave LDS in-order; the
// compiler's data wait on the readback covers the write). (5) pj prefetch.
// Stage schedule (epoch e): w0 a0rec@e | w4,5 a1proj@e-1 | w1 a1rec@e-2 |
// w6,7 a2proj@e-3 | w2 a2rec@e-4 | w3 b-chain@e-5.

#define BB 256
#define TT 512
#define CH 8
#define NS 16  // ring slots = 2*CH

typedef _Float16 v2h __attribute__((ext_vector_type(2)));

__device__ __forceinline__ float sig_(float x) {
  return __builtin_amdgcn_rcpf(1.f + __builtin_amdgcn_exp2f(-1.44269504f * x));
}
__device__ __forceinline__ float tanh_(float x) {
  return __builtin_fmaf(2.f, __builtin_amdgcn_rcpf(1.f + __builtin_amdgcn_exp2f(-2.88539008f * x)), -1.f);
}

template <int K>
__device__ __forceinline__ float qb_(float v) {
  return __int_as_float(__builtin_amdgcn_update_dpp(
      0, __float_as_int(v), (K | (K << 2) | (K << 4) | (K << 6)), 0xF, 0xF, true));
}

__device__ __forceinline__ void ldsbar_() {
  asm volatile("s_waitcnt lgkmcnt(0)\n\ts_barrier" ::: "memory");
}

#if __has_builtin(__builtin_amdgcn_fdot2)
#define FDOT2(acc, a, b) (acc) = __builtin_amdgcn_fdot2((a), (b), (acc), false)
#else
#define FDOT2(acc, a, b) \
  (acc) = __builtin_fmaf((float)(a)[0], (float)(b)[0], \
          __builtin_fmaf((float)(a)[1], (float)(b)[1], (acc)))
#endif

#if __has_builtin(__builtin_elementwise_fma)
#define PKFMA(acc, a, b) (acc) = __builtin_elementwise_fma((a), (b), (acc))
#else
#define PKFMA(acc, a, b) (acc) += (a) * (b)
#endif

#define KEEPP(a) asm volatile("" : "+v"(a))
#define PIN32(w)                                                            \
  do {                                                                      \
    _Pragma("unroll") for (int _i = 0; _i < 32; ++_i) KEEPP((w)[_i]);       \
  } while (0)

__device__ __forceinline__ v2h bc2h_(int v) { return __builtin_bit_cast(v2h, v); }

// 64 halfs from LDS as 32 v2h via int4 reads (8x ds_read_b128).
__device__ __forceinline__ void load_h64(const _Float16* p, v2h hv[32]) {
  const int4* hp = reinterpret_cast<const int4*>(p);
#pragma unroll
  for (int i = 0; i < 8; ++i) {
    int4 blk = hp[i];
    hv[4 * i + 0] = bc2h_(blk.x);
    hv[4 * i + 1] = bc2h_(blk.y);
    hv[4 * i + 2] = bc2h_(blk.z);
    hv[4 * i + 3] = bc2h_(blk.w);
  }
}

// fp32 row of 64 -> 32 v2h.
__device__ __forceinline__ void load_row16(const float* src, v2h dst[32]) {
  const float4* p = reinterpret_cast<const float4*>(src);
#pragma unroll
  for (int i = 0; i < 16; ++i) {
    float4 v = p[i];
    dst[2 * i]     = v2h{(_Float16)v.x, (_Float16)v.y};
    dst[2 * i + 1] = v2h{(_Float16)v.z, (_Float16)v.w};
  }
}

// 4-gate dot via v_pk_fma_f16: 2 v2h accumulators per gate (depth-16 f16
// chains), f32 combine via fdot2 with ones. p holds init value (bias).
__device__ __forceinline__ void dot4pk_(const v2h w[4][32], const v2h hv[32],
                                        float& p0, float& p1, float& p2, float& p3) {
  v2h a0{}, a1{}, a2{}, a3{}, b0{}, b1{}, b2{}, b3{};
#pragma unroll
  for (int j = 0; j < 32; j += 2) {
    PKFMA(a0, w[0][j], hv[j]);         PKFMA(a1, w[1][j], hv[j]);
    PKFMA(a2, w[2][j], hv[j]);         PKFMA(a3, w[3][j], hv[j]);
    PKFMA(b0, w[0][j + 1], hv[j + 1]); PKFMA(b1, w[1][j + 1], hv[j + 1]);
    PKFMA(b2, w[2][j + 1], hv[j + 1]); PKFMA(b3, w[3][j + 1], hv[j + 1]);
  }
  const v2h one = {(_Float16)1.f, (_Float16)1.f};
  FDOT2(p0, a0, one); FDOT2(p1, a1, one); FDOT2(p2, a2, one); FDOT2(p3, a3, one);
  FDOT2(p0, b0, one); FDOT2(p1, b1, one); FDOT2(p2, b2, one); FDOT2(p3, b3, one);
}

// 2-gate dot (projection halves), pk_fma version.
__device__ __forceinline__ void dot2gpk_(const v2h* w0, const v2h* w1,
                                         const v2h hv[32], float& p0, float& p1) {
  v2h a0{}, a1{}, b0{}, b1{};
#pragma unroll
  for (int j = 0; j < 32; j += 2) {
    PKFMA(a0, w0[j], hv[j]);         PKFMA(a1, w1[j], hv[j]);
    PKFMA(b0, w0[j + 1], hv[j + 1]); PKFMA(b1, w1[j + 1], hv[j + 1]);
  }
  const v2h one = {(_Float16)1.f, (_Float16)1.f};
  float r0 = 0.f, r1 = 0.f;
  FDOT2(r0, a0, one); FDOT2(r1, a1, one);
  FDOT2(r0, b0, one); FDOT2(r1, b1, one);
  p0 = r0; p1 = r1;
}

__global__ __attribute__((amdgpu_flat_work_group_size(512, 512),
                          amdgpu_waves_per_eu(2, 2)))
void lstm_pipe_k(
    const float* __restrict__ x,
    const float* __restrict__ wih_a0, const float* __restrict__ whh_a0,
    const float* __restrict__ bih_a0, const float* __restrict__ bhh_a0,
    const float* __restrict__ wih_a1, const float* __restrict__ whh_a1,
    const float* __restrict__ bih_a1, const float* __restrict__ bhh_a1,
    const float* __restrict__ wih_a2, const float* __restrict__ whh_a2,
    const float* __restrict__ bih_a2, const float* __restrict__ bhh_a2,
    const float* __restrict__ wih_b0, const float* __restrict__ whh_b0,
    const float* __restrict__ bih_b0, const float* __restrict__ bhh_b0,
    const float* __restrict__ wih_b1, const float* __restrict__ whh_b1,
    const float* __restrict__ bih_b1, const float* __restrict__ bhh_b1,
    const float* __restrict__ wih_b2, const float* __restrict__ whh_b2,
    const float* __restrict__ bih_b2, const float* __restrict__ bhh_b2,
    float* __restrict__ out)  // [B,T]
{
  // Force arch-VGPR count to ~208 so pk_fma/fdot2 (VOP3P, AGPR-blind) can
  // address the resident weights directly (see header).
  asm volatile("" ::: "v204", "v205", "v206", "v207");

  const int b = blockIdx.x;
  const int tid = threadIdx.x;
  const int wave = tid >> 6;
  const int lane = tid & 63;

  __shared__ __align__(16) _Float16 hh[3][NS][64];  // h rings
  __shared__ __align__(16) float pj[2][NS][256];    // proj rings [hid][gate]
  __shared__ float xs[TT];

  for (int i = tid; i < TT; i += 512) xs[i] = x[(size_t)b * TT + i];
  for (int i = tid; i < 3 * NS * 64 / 2; i += 512) reinterpret_cast<int*>(hh)[i] = 0;

  v2h wt[4][32];
  float bias[4] = {0.f, 0.f, 0.f, 0.f};
  float wi0_[4] = {0.f, 0.f, 0.f, 0.f};
  float whb0[4] = {}, wi1b[4] = {}, wh1b[4] = {}, bb1[4] = {},
        wi2b[4] = {}, wh2b[4] = {}, bb2[4] = {};

  if (wave == 0) {  // a0 recurrence
#pragma unroll
    for (int q = 0; q < 4; ++q) {
      const int row = q * 64 + lane;
      load_row16(whh_a0 + row * 64, wt[q]);
      bias[q] = bih_a0[row] + bhh_a0[row];
      wi0_[q] = wih_a0[row];
    }
    PIN32(wt[0]); PIN32(wt[1]); PIN32(wt[2]); PIN32(wt[3]);
  } else if (wave == 1) {  // a1 recurrence
#pragma unroll
    for (int q = 0; q < 4; ++q) {
      const int row = q * 64 + lane;
      load_row16(whh_a1 + row * 64, wt[q]);
      bias[q] = bih_a1[row] + bhh_a1[row];
    }
    PIN32(wt[0]); PIN32(wt[1]); PIN32(wt[2]); PIN32(wt[3]);
  } else if (wave == 2) {  // a2 recurrence
#pragma unroll
    for (int q = 0; q < 4; ++q) {
      const int row = q * 64 + lane;
      load_row16(whh_a2 + row * 64, wt[q]);
      bias[q] = bih_a2[row] + bhh_a2[row];
    }
    PIN32(wt[0]); PIN32(wt[1]); PIN32(wt[2]); PIN32(wt[3]);
  } else if (wave == 3) {  // b-chain
    const int q = lane & 3;
    load_row16(wih_b0 + q * 64, wt[0]);
    bias[0] = bih_b0[q] + bhh_b0[q];
#pragma unroll
    for (int k = 0; k < 4; ++k) {
      whb0[k] = whh_b0[k];
      wi1b[k] = wih_b1[k]; wh1b[k] = whh_b1[k]; bb1[k] = bih_b1[k] + bhh_b1[k];
      wi2b[k] = wih_b2[k]; wh2b[k] = whh_b2[k]; bb2[k] = bih_b2[k] + bhh_b2[k];
    }
    PIN32(wt[0]);
  } else if (wave == 4) {  // a1 proj gates 0,1
#pragma unroll
    for (int q = 0; q < 2; ++q) load_row16(wih_a1 + (q * 64 + lane) * 64, wt[q]);
    PIN32(wt[0]); PIN32(wt[1]);
  } else if (wave == 5) {  // a1 proj gates 2,3
#pragma unroll
    for (int q = 0; q < 2; ++q) load_row16(wih_a1 + ((q + 2) * 64 + lane) * 64, wt[q]);
    PIN32(wt[0]); PIN32(wt[1]);
  } else if (wave == 6) {  // a2 proj gates 0,1
#pragma unroll
    for (int q = 0; q < 2; ++q) load_row16(wih_a2 + (q * 64 + lane) * 64, wt[q]);
    PIN32(wt[0]); PIN32(wt[1]);
  } else {                 // a2 proj gates 2,3
#pragma unroll
    for (int q = 0; q < 2; ++q) load_row16(wih_a2 + ((q + 2) * 64 + lane) * 64, wt[q]);
    PIN32(wt[0]); PIN32(wt[1]);
  }
  __syncthreads();

  float c = 0.f;
  float h0b = 0.f, c0b = 0.f, h1b = 0.f, c1b = 0.f, h2b = 0.f, c2b = 0.f;

  const int NE = TT / CH + 5;
  for (int e = 0; e < NE; ++e) {
    if (wave == 0) {  // a0 rec, window e
      const int t0 = e * CH;
      if (t0 < TT) {
        __builtin_amdgcn_s_setprio(1);
        for (int s = 0; s < CH; ++s) {
          const int t = t0 + s;
          v2h hv[32];
          load_h64(&hh[0][(t + NS - 1) & (NS - 1)][0], hv);
          const float xv = xs[t];
          float p0 = bias[0], p1 = bias[1], p2 = bias[2], p3 = bias[3];
          dot4pk_(wt, hv, p0, p1, p2, p3);
          p0 = __builtin_fmaf(wi0_[0], xv, p0);
          p1 = __builtin_fmaf(wi0_[1], xv, p1);
          p2 = __builtin_fmaf(wi0_[2], xv, p2);
          p3 = __builtin_fmaf(wi0_[3], xv, p3);
          float gi = sig_(p0), gf = sig_(p1), gg = tanh_(p2), go = sig_(p3);
          c = __builtin_fmaf(gf, c, gi * gg);
          hh[0][t & (NS - 1)][lane] = (_Float16)(go * tanh_(c));
        }
        __builtin_amdgcn_s_setprio(0);
      }
    } else if (wave == 1) {  // a1 rec, window e-2
      const int t0 = (e - 2) * CH;
      if (t0 >= 0 && t0 < TT) {
        __builtin_amdgcn_s_setprio(1);
        float4 pr = *reinterpret_cast<const float4*>(&pj[0][t0 & (NS - 1)][lane * 4]);
        for (int s = 0; s < CH; ++s) {
          const int t = t0 + s;
          v2h hv[32];
          load_h64(&hh[1][(t + NS - 1) & (NS - 1)][0], hv);
          float4 prn = pr;
          if (s + 1 < CH)
            prn = *reinterpret_cast<const float4*>(&pj[0][(t + 1) & (NS - 1)][lane * 4]);
          float p0 = bias[0], p1 = bias[1], p2 = bias[2], p3 = bias[3];
          dot4pk_(wt, hv, p0, p1, p2, p3);
          p0 += pr.x; p1 += pr.y; p2 += pr.z; p3 += pr.w;
          float gi = sig_(p0), gf = sig_(p1), gg = tanh_(p2), go = sig_(p3);
          c = __builtin_fmaf(gf, c, gi * gg);
          hh[1][t & (NS - 1)][lane] = (_Float16)(go * tanh_(c));
          pr = prn;
        }
        __builtin_amdgcn_s_setprio(0);
      }
    } else if (wave == 2) {  // a2 rec, window e-4
      const int t0 = (e - 4) * CH;
      if (t0 >= 0 && t0 < TT) {
        __builtin_amdgcn_s_setprio(1);
        float4 pr = *reinterpret_cast<const float4*>(&pj[1][t0 & (NS - 1)][lane * 4]);
        for (int s = 0; s < CH; ++s) {
          const int t = t0 + s;
          v2h hv[32];
          load_h64(&hh[2][(t + NS - 1) & (NS - 1)][0], hv);
          float4 prn = pr;
          if (s + 1 < CH)
            prn = *reinterpret_cast<const float4*>(&pj[1][(t + 1) & (NS - 1)][lane * 4]);
          float p0 = bias[0], p1 = bias[1], p2 = bias[2], p3 = bias[3];
          dot4pk_(wt, hv, p0, p1, p2, p3);
          p0 += pr.x; p1 += pr.y; p2 += pr.z; p3 += pr.w;
          float gi = sig_(p0), gf = sig_(p1), gg = tanh_(p2), go = sig_(p3);
          c = __builtin_fmaf(gf, c, gi * gg);
          hh[2][t & (NS - 1)][lane] = (_Float16)(go * tanh_(c));
          pr = prn;
        }
        __builtin_amdgcn_s_setprio(0);
      }
    } else if (wave == 3) {  // b-chain, window e-5
      const int t0 = (e - 5) * CH;
      if (t0 >= 0 && t0 < TT) {
        for (int s = 0; s < CH; ++s) {
          const int t = t0 + s;
          v2h hv[32];
          load_h64(&hh[2][t & (NS - 1)][0], hv);
          v2h pa{}, pb{};
#pragma unroll
          for (int j = 0; j < 32; j += 2) {
            PKFMA(pa, wt[0][j], hv[j]);
            PKFMA(pb, wt[0][j + 1], hv[j + 1]);
          }
          const v2h one = {(_Float16)1.f, (_Float16)1.f};
          float pg = bias[0];
          FDOT2(pg, pa, one);
          FDOT2(pg, pb, one);
          float p_i = qb_<0>(pg), p_f = qb_<1>(pg), p_g = qb_<2>(pg), p_o = qb_<3>(pg);
          float i0 = sig_(__builtin_fmaf(whb0[0], h0b, p_i));
          float f0 = sig_(__builtin_fmaf(whb0[1], h0b, p_f));
          float g0 = tanh_(__builtin_fmaf(whb0[2], h0b, p_g));
          float o0 = sig_(__builtin_fmaf(whb0[3], h0b, p_o));
          c0b = __builtin_fmaf(f0, c0b, i0 * g0);
          h0b = o0 * tanh_(c0b);
          float i1 = sig_(bb1[0] + __builtin_fmaf(wi1b[0], h0b, wh1b[0] * h1b));
          float f1 = sig_(bb1[1] + __builtin_fmaf(wi1b[1], h0b, wh1b[1] * h1b));
          float g1 = tanh_(bb1[2] + __builtin_fmaf(wi1b[2], h0b, wh1b[2] * h1b));
          float o1 = sig_(bb1[3] + __builtin_fmaf(wi1b[3], h0b, wh1b[3] * h1b));
          c1b = __builtin_fmaf(f1, c1b, i1 * g1);
          h1b = o1 * tanh_(c1b);
          float i2 = sig_(bb2[0] + __builtin_fmaf(wi2b[0], h1b, wh2b[0] * h2b));
          float f2 = sig_(bb2[1] + __builtin_fmaf(wi2b[1], h1b, wh2b[1] * h2b));
          float g2 = tanh_(bb2[2] + __builtin_fmaf(wi2b[2], h1b, wh2b[2] * h2b));
          float o2 = sig_(bb2[3] + __builtin_fmaf(wi2b[3], h1b, wh2b[3] * h2b));
          c2b = __builtin_fmaf(f2, c2b, i2 * g2);
          h2b = o2 * tanh_(c2b);
          if (lane == 0) out[(size_t)b * TT + t] = h2b;
        }
      }
    } else if (wave == 4) {  // a1 proj g01, window e-1
      const int t0 = (e - 1) * CH;
      if (t0 >= 0 && t0 < TT) {
        for (int s = 0; s < CH; ++s) {
          const int t = t0 + s;
          v2h hv[32];
          load_h64(&hh[0][t & (NS - 1)][0], hv);
          float p0, p1;
          dot2gpk_(wt[0], wt[1], hv, p0, p1);
          *reinterpret_cast<float2*>(&pj[0][t & (NS - 1)][lane * 4]) = float2{p0, p1};
        }
      }
    } else if (wave == 5) {  // a1 proj g23, window e-1
      const int t0 = (e - 1) * CH;
      if (t0 >= 0 && t0 < TT) {
        for (int s = 0; s < CH; ++s) {
          const int t = t0 + s;
          v2h hv[32];
          load_h64(&hh[0][t & (NS - 1)][0], hv);
          float p2, p3;
          dot2gpk_(wt[0], wt[1], hv, p2, p3);
          *reinterpret_cast<float2*>(&pj[0][t & (NS - 1)][lane * 4 + 2]) = float2{p2, p3};
        }
      }
    } else if (wave == 6) {  // a2 proj g01, window e-3
      const int t0 = (e - 3) * CH;
      if (t0 >= 0 && t0 < TT) {
        for (int s = 0; s < CH; ++s) {
          const int t = t0 + s;
          v2h hv[32];
          load_h64(&hh[1][t & (NS - 1)][0], hv);
          float p0, p1;
          dot2gpk_(wt[0], wt[1], hv, p0, p1);
          *reinterpret_cast<float2*>(&pj[1][t & (NS - 1)][lane * 4]) = float2{p0, p1};
        }
      }
    } else {                 // a2 proj g23, window e-3
      const int t0 = (e - 3) * CH;
      if (t0 >= 0 && t0 < TT) {
        for (int s = 0; s < CH; ++s) {
          const int t = t0 + s;
          v2h hv[32];
          load_h64(&hh[1][t & (NS - 1)][0], hv);
          float p2, p3;
          dot2gpk_(wt[0], wt[1], hv, p2, p3);
          *reinterpret_cast<float2*>(&pj[1][t & (NS - 1)][lane * 4 + 2]) = float2{p2, p3};
        }
      }
    }
    ldsbar_();
  }
}

extern "C" void kernel_launch(void* const* d_in, const int* in_sizes, int n_in,
                              void* d_out, int out_size, void* d_ws, size_t ws_size,
                              hipStream_t stream) {
  const float* x      = (const float*)d_in[0];
  const float* wih_a0 = (const float*)d_in[1];
  const float* whh_a0 = (const float*)d_in[2];
  const float* bih_a0 = (const float*)d_in[3];
  const float* bhh_a0 = (const float*)d_in[4];
  const float* wih_a1 = (const float*)d_in[5];
  const float* whh_a1 = (const float*)d_in[6];
  const float* bih_a1 = (const float*)d_in[7];
  const float* bhh_a1 = (const float*)d_in[8];
  const float* wih_a2 = (const float*)d_in[9];
  const float* whh_a2 = (const float*)d_in[10];
  const float* bih_a2 = (const float*)d_in[11];
  const float* bhh_a2 = (const float*)d_in[12];
  const float* wih_b0 = (const float*)d_in[13];
  const float* whh_b0 = (const float*)d_in[14];
  const float* bih_b0 = (const float*)d_in[15];
  const float* bhh_b0 = (const float*)d_in[16];
  const float* wih_b1 = (const float*)d_in[17];
  const float* whh_b1 = (const float*)d_in[18];
  const float* bih_b1 = (const float*)d_in[19];
  const float* bhh_b1 = (const float*)d_in[20];
  const float* wih_b2 = (const float*)d_in[21];
  const float* whh_b2 = (const float*)d_in[22];
  const float* bih_b2 = (const float*)d_in[23];
  const float* bhh_b2 = (const float*)d_in[24];
  float* out = (float*)d_out;

  lstm_pipe_k<<<BB, 512, 0, stream>>>(
      x,
      wih_a0, whh_a0, bih_a0, bhh_a0,
      wih_a1, whh_a1, bih_a1, bhh_a1,
      wih_a2, whh_a2, bih_a2, bhh_a2,
      wih_b0, whh_b0, bih_b0, bhh_b0,
      wih_b1, whh_b1, bih_b1, bhh_b1,
      wih_b2, whh_b2, bih_b2, bhh_b2,
      out);
}